// Round 1
// baseline (145.386 us; speedup 1.0000x reference)
//
#include <hip/hip_runtime.h>
#include <hip/hip_bf16.h>

typedef __bf16 bf16_t;
typedef __bf16 bf16x8 __attribute__((ext_vector_type(8)));
typedef float  f32x4  __attribute__((ext_vector_type(4)));

#define GLL16(gp, lp) __builtin_amdgcn_global_load_lds(                        \
    (const __attribute__((address_space(1))) unsigned int*)(gp),               \
    (__attribute__((address_space(3))) unsigned int*)(lp), 16, 0, 0)

__device__ __forceinline__ float fast_sigmoid(float x) {
    return 1.f / (1.f + __expf(-x));
}
__device__ __forceinline__ float fast_tanh(float x) {
    float ax = fabsf(x);
    float t  = __expf(-2.f * ax);
    float r  = (1.f - t) / (1.f + t);
    return copysignf(r, x);
}

// ---------------- pack kernels: fp32 -> bf16 ----------------

// combined A[b][k] : k<512 from inputs, k>=512 from hidden. [16384][1024]
__global__ void pack_combined(const float* __restrict__ inp,
                              const float* __restrict__ hid,
                              bf16_t* __restrict__ A) {
    const size_t total = (size_t)16384 * 128;  // chunks of 8 elems
    size_t i = (size_t)blockIdx.x * blockDim.x + threadIdx.x;
    const size_t stride = (size_t)gridDim.x * blockDim.x;
    for (; i < total; i += stride) {
        size_t b = i >> 7;
        int kc = (int)(i & 127);
        const float* src = (kc < 64) ? (inp + b * 512 + kc * 8)
                                     : (hid + b * 512 + (kc - 64) * 8);
        float4 f0 = *(const float4*)src;
        float4 f1 = *(const float4*)(src + 4);
        bf16x8 v;
        v[0] = (bf16_t)f0.x; v[1] = (bf16_t)f0.y; v[2] = (bf16_t)f0.z; v[3] = (bf16_t)f0.w;
        v[4] = (bf16_t)f1.x; v[5] = (bf16_t)f1.y; v[6] = (bf16_t)f1.z; v[7] = (bf16_t)f1.w;
        *(bf16x8*)(A + i * 8) = v;
    }
}

// W_bf [4][512][1024], gate order: 0=f,1=i,2=o,3=c
__global__ void pack_W(const float* __restrict__ wf, const float* __restrict__ wi,
                       const float* __restrict__ wo, const float* __restrict__ wc,
                       bf16_t* __restrict__ dst) {
    size_t idx = (size_t)blockIdx.x * blockDim.x + threadIdx.x;  // 262144 total
    int g = (int)(idx >> 16);
    size_t off = idx & 65535;
    const float* src = (g == 0) ? wf : (g == 1) ? wi : (g == 2) ? wo : wc;
    float4 f0 = ((const float4*)src)[off * 2];
    float4 f1 = ((const float4*)src)[off * 2 + 1];
    bf16x8 v;
    v[0] = (bf16_t)f0.x; v[1] = (bf16_t)f0.y; v[2] = (bf16_t)f0.z; v[3] = (bf16_t)f0.w;
    v[4] = (bf16_t)f1.x; v[5] = (bf16_t)f1.y; v[6] = (bf16_t)f1.z; v[7] = (bf16_t)f1.w;
    ((bf16x8*)dst)[idx] = v;
}

__global__ void cvt8(const float* __restrict__ src, bf16_t* __restrict__ dst, size_t n8) {
    size_t i = (size_t)blockIdx.x * blockDim.x + threadIdx.x;
    if (i >= n8) return;
    float4 f0 = ((const float4*)src)[i * 2];
    float4 f1 = ((const float4*)src)[i * 2 + 1];
    bf16x8 v;
    v[0] = (bf16_t)f0.x; v[1] = (bf16_t)f0.y; v[2] = (bf16_t)f0.z; v[3] = (bf16_t)f0.w;
    v[4] = (bf16_t)f1.x; v[5] = (bf16_t)f1.y; v[6] = (bf16_t)f1.z; v[7] = (bf16_t)f1.w;
    ((bf16x8*)dst)[i] = v;
}

// ---------------- fused 4-gate GEMM + LSTM elementwise epilogue ----------------
// gates[b][g][j] = sum_k A[b][k] * W[g][j][k] + bias_g[j]
// Block: 128 rows x 32 j-cols x 4 gates. 4 waves (2 M x 2 j).
__global__ void gemm_gates(const bf16_t* __restrict__ A,     // [16384][1024]
                           const bf16_t* __restrict__ W,     // [4][512][1024]
                           const float* __restrict__ bF, const float* __restrict__ bI,
                           const float* __restrict__ bO, const float* __restrict__ bC,
                           const float* __restrict__ cell,   // [16384][512]
                           float* __restrict__ out_cell,
                           float* __restrict__ out_hid,
                           bf16_t* __restrict__ hid_bf) {
    constexpr int K = 1024;
    const int tid  = threadIdx.x;
    const int lane = tid & 63;
    const int wid  = tid >> 6;
    const int wm   = wid >> 1;   // 0..1 over M
    const int wj   = wid & 1;    // 0..1 over j
    const int mtile = blockIdx.y * 128;
    const int jtile = blockIdx.x * 32;

    __shared__ __align__(16) unsigned char sA[128 * 64];  // [128 rows][32 bf16], swizzled
    __shared__ __align__(16) unsigned char sW[128 * 64];  // [4*32 rows][32 bf16], swizzled

    f32x4 acc[4][4];
#pragma unroll
    for (int g = 0; g < 4; ++g)
#pragma unroll
        for (int m = 0; m < 4; ++m) acc[g][m] = f32x4{0.f, 0.f, 0.f, 0.f};

    // staging descriptors: 2 rounds each for A and W (8KB each, 4KB/round)
    const bf16_t* gA[2]; const bf16_t* gW[2];
    unsigned ldsOff[2];
#pragma unroll
    for (int q = 0; q < 2; ++q) {
        int ch = q * 4 + wid;               // 0..7
        int r  = ch * 16 + (lane >> 2);     // row 0..127
        int cphys = lane & 3;
        int clog  = cphys ^ ((r >> 1) & 3); // XOR swizzle (involution)
        gA[q] = A + (size_t)(mtile + r) * K + clog * 8;
        int g = r >> 5, j = r & 31;
        gW[q] = W + (size_t)(g * 512 + jtile + j) * K + clog * 8;
        ldsOff[q] = (unsigned)ch * 1024;
    }

    for (int k0 = 0; k0 < K; k0 += 32) {
#pragma unroll
        for (int q = 0; q < 2; ++q) {
            GLL16(gA[q] + k0, sA + ldsOff[q]);
            GLL16(gW[q] + k0, sW + ldsOff[q]);
        }
        __syncthreads();  // drains vmcnt -> staged data visible

        bf16x8 af[4], wf[4];
#pragma unroll
        for (int m = 0; m < 4; ++m) {
            int r = wm * 64 + m * 16 + (lane & 15);
            int c = (lane >> 4) ^ ((r >> 1) & 3);
            af[m] = *reinterpret_cast<const bf16x8*>(sA + r * 64 + c * 16);
        }
#pragma unroll
        for (int g = 0; g < 4; ++g) {
            int rr = g * 32 + wj * 16 + (lane & 15);
            int c  = (lane >> 4) ^ ((rr >> 1) & 3);
            wf[g] = *reinterpret_cast<const bf16x8*>(sW + rr * 64 + c * 16);
        }
#pragma unroll
        for (int g = 0; g < 4; ++g)
#pragma unroll
            for (int m = 0; m < 4; ++m)
                acc[g][m] = __builtin_amdgcn_mfma_f32_16x16x32_bf16(af[m], wf[g], acc[g][m], 0, 0, 0);
        __syncthreads();
    }

    // epilogue: C[row][col] with col=lane&15, row=(lane>>4)*4+e  (m89-verified)
    const int col = lane & 15;
    const int j   = jtile + wj * 16 + col;
    const float bf_ = bF[j], bi_ = bI[j], bo_ = bO[j], bc_ = bC[j];
#pragma unroll
    for (int m = 0; m < 4; ++m) {
#pragma unroll
        for (int e = 0; e < 4; ++e) {
            int row = mtile + wm * 64 + m * 16 + (lane >> 4) * 4 + e;
            float fg = fast_sigmoid(acc[0][m][e] + bf_);
            float ig = fast_sigmoid(acc[1][m][e] + bi_);
            float og = fast_sigmoid(acc[2][m][e] + bo_);
            float cg = fast_tanh(acc[3][m][e] + bc_);
            size_t idx = (size_t)row * 512 + j;
            float cs = cell[idx];
            float nc = fg * cs + ig * cg;
            float nh = og * fast_tanh(nc);
            out_cell[idx] = nc;
            out_hid[idx]  = nh;
            hid_bf[idx]   = (bf16_t)nh;
        }
    }
}

// ---------------- output GEMM: out = hid @ V^T + vb ----------------
__global__ void gemm_out(const bf16_t* __restrict__ Ah,   // [16384][512]
                         const bf16_t* __restrict__ V,    // [512][512] (row n, col k)
                         const float* __restrict__ vb,
                         float* __restrict__ out) {
    constexpr int K = 512;
    const int tid  = threadIdx.x;
    const int lane = tid & 63;
    const int wid  = tid >> 6;
    const int wm   = wid >> 1;
    const int wn   = wid & 1;
    const int mtile = blockIdx.y * 128;
    const int ntile = blockIdx.x * 128;

    __shared__ __align__(16) unsigned char sA[128 * 64];
    __shared__ __align__(16) unsigned char sB[128 * 64];

    f32x4 acc[4][4];  // [n-frag][m-frag]
#pragma unroll
    for (int n = 0; n < 4; ++n)
#pragma unroll
        for (int m = 0; m < 4; ++m) acc[n][m] = f32x4{0.f, 0.f, 0.f, 0.f};

    const bf16_t* gA[2]; const bf16_t* gB[2];
    unsigned ldsOff[2];
#pragma unroll
    for (int q = 0; q < 2; ++q) {
        int ch = q * 4 + wid;
        int r  = ch * 16 + (lane >> 2);
        int cphys = lane & 3;
        int clog  = cphys ^ ((r >> 1) & 3);
        gA[q] = Ah + (size_t)(mtile + r) * K + clog * 8;
        gB[q] = V  + (size_t)(ntile + r) * K + clog * 8;
        ldsOff[q] = (unsigned)ch * 1024;
    }

    for (int k0 = 0; k0 < K; k0 += 32) {
#pragma unroll
        for (int q = 0; q < 2; ++q) {
            GLL16(gA[q] + k0, sA + ldsOff[q]);
            GLL16(gB[q] + k0, sB + ldsOff[q]);
        }
        __syncthreads();

        bf16x8 af[4], bfv[4];
#pragma unroll
        for (int m = 0; m < 4; ++m) {
            int r = wm * 64 + m * 16 + (lane & 15);
            int c = (lane >> 4) ^ ((r >> 1) & 3);
            af[m] = *reinterpret_cast<const bf16x8*>(sA + r * 64 + c * 16);
        }
#pragma unroll
        for (int n = 0; n < 4; ++n) {
            int r = wn * 64 + n * 16 + (lane & 15);
            int c = (lane >> 4) ^ ((r >> 1) & 3);
            bfv[n] = *reinterpret_cast<const bf16x8*>(sB + r * 64 + c * 16);
        }
#pragma unroll
        for (int n = 0; n < 4; ++n)
#pragma unroll
            for (int m = 0; m < 4; ++m)
                acc[n][m] = __builtin_amdgcn_mfma_f32_16x16x32_bf16(af[m], bfv[n], acc[n][m], 0, 0, 0);
        __syncthreads();
    }

    const int cl = lane & 15;
#pragma unroll
    for (int n = 0; n < 4; ++n) {
        int coln = ntile + wn * 64 + n * 16 + cl;
        float b = vb[coln];
#pragma unroll
        for (int m = 0; m < 4; ++m) {
#pragma unroll
            for (int e = 0; e < 4; ++e) {
                int row = mtile + wm * 64 + m * 16 + (lane >> 4) * 4 + e;
                out[(size_t)row * 512 + coln] = acc[n][m][e] + b;
            }
        }
    }
}

extern "C" void kernel_launch(void* const* d_in, const int* in_sizes, int n_in,
                              void* d_out, int out_size, void* d_ws, size_t ws_size,
                              hipStream_t stream) {
    const float* inputs = (const float*)d_in[0];
    const float* cell   = (const float*)d_in[1];
    const float* hidden = (const float*)d_in[2];
    const float* Wf_w = (const float*)d_in[3];
    const float* Wf_b = (const float*)d_in[4];
    const float* Wi_w = (const float*)d_in[5];
    const float* Wi_b = (const float*)d_in[6];
    const float* Wc_w = (const float*)d_in[7];
    const float* Wc_b = (const float*)d_in[8];
    const float* Wo_w = (const float*)d_in[9];
    const float* Wo_b = (const float*)d_in[10];
    const float* V_w  = (const float*)d_in[11];
    const float* V_b  = (const float*)d_in[12];
    float* out = (float*)d_out;

    char* ws = (char*)d_ws;
    bf16_t* A_bf = (bf16_t*)(ws);                                  // 32 MB
    bf16_t* W_bf = (bf16_t*)(ws + 33554432);                       // 4 MB
    bf16_t* V_bf = (bf16_t*)(ws + 33554432 + 4194304);             // 0.5 MB
    bf16_t* h_bf = (bf16_t*)(ws + 33554432 + 4194304 + 524288);    // 16 MB

    pack_combined<<<2048, 256, 0, stream>>>(inputs, hidden, A_bf);
    pack_W<<<1024, 256, 0, stream>>>(Wf_w, Wi_w, Wo_w, Wc_w, W_bf);
    cvt8<<<128, 256, 0, stream>>>(V_w, V_bf, 32768);

    // gate GEMM + fused LSTM elementwise; writes new_cell, new_hidden, hid_bf16
    gemm_gates<<<dim3(16, 128), 256, 0, stream>>>(
        A_bf, W_bf, Wf_b, Wi_b, Wo_b, Wc_b, cell,
        out, out + (size_t)16384 * 512, h_bf);

    // output GEMM
    gemm_out<<<dim3(4, 128), 256, 0, stream>>>(
        h_bf, V_bf, V_b, out + (size_t)2 * 16384 * 512);
}